// Round 1
// baseline (940.490 us; speedup 1.0000x reference)
//
#include <hip/hip_runtime.h>
#include <hip/hip_bf16.h>
#include <math.h>

// GAT forward: N=50000 nodes, E=1.6M edges, F_IN=64, HID=128, HEADS=8, D_HEAD=16, 2 layers.
// Strategy: CSR-by-dst build (hist/scan/scatter), fp32 LDS-staged GEMMs with fused
// alpha_src/alpha_dst, then one wave per destination node doing softmax+aggregation+
// bias+ELU+residual+LayerNorm fused, atomic-free.

#define F_IN 64
#define HID 128
#define HEADS 8
#define CHUNK 128   // edges per softmax chunk staged in LDS

// ---------------- CSR build ----------------

__global__ void zero_i32_kernel(int* __restrict__ p, int n) {
    int i = blockIdx.x * blockDim.x + threadIdx.x;
    if (i < n) p[i] = 0;
}

// Detect whether edge_index arrived as int64 (little-endian: odd 32-bit words are
// the high halves, all zero since node ids < 50000) or as int32.
__global__ void detect64_kernel(const int* __restrict__ ei, int* __restrict__ flag) {
    if (threadIdx.x == 0 && blockIdx.x == 0) {
        int any_odd = 0;
        for (int i = 0; i < 256; i++) any_odd |= ei[2 * i + 1];
        *flag = (any_odd == 0) ? 1 : 0;   // 1 => int64 layout
    }
}

__device__ __forceinline__ int edge_src(const int* ei, int E, int i, int is64) {
    return is64 ? ei[2 * i] : ei[i];
}
__device__ __forceinline__ int edge_dst(const int* ei, int E, int i, int is64) {
    return is64 ? ei[2 * (E + i)] : ei[E + i];
}

__global__ void hist_kernel(const int* __restrict__ ei, int E,
                            const int* __restrict__ flag, int* __restrict__ counts) {
    int is64 = *flag;
    for (int i = blockIdx.x * blockDim.x + threadIdx.x; i < E; i += gridDim.x * blockDim.x) {
        atomicAdd(&counts[edge_dst(ei, E, i, is64)], 1);
    }
}

// Single-block scan over N counters. counts_cursor is read (counts) and rewritten
// (per-dst cursor = exclusive prefix). row_ptr gets the CSR offsets, row_ptr[n]=E.
__global__ void scan_kernel(int* __restrict__ counts_cursor, int* __restrict__ row_ptr, int n) {
    __shared__ int sums[1024];
    int t = threadIdx.x;
    int chunk = (n + 1023) >> 10;
    int b0 = t * chunk;
    int b1 = min(n, b0 + chunk);
    int s = 0;
    for (int i = b0; i < b1; i++) s += counts_cursor[i];
    sums[t] = s;
    __syncthreads();
    for (int off = 1; off < 1024; off <<= 1) {
        int add = (t >= off) ? sums[t - off] : 0;
        __syncthreads();
        sums[t] += add;
        __syncthreads();
    }
    int run = sums[t] - s;   // exclusive prefix at b0
    for (int i = b0; i < b1; i++) {
        int c = counts_cursor[i];
        row_ptr[i] = run;
        counts_cursor[i] = run;
        run += c;
    }
    if (t == 0) row_ptr[n] = sums[1023];
}

__global__ void scatter_kernel(const int* __restrict__ ei, int E,
                               const int* __restrict__ flag,
                               int* __restrict__ cursor, int* __restrict__ src_sorted) {
    int is64 = *flag;
    for (int i = blockIdx.x * blockDim.x + threadIdx.x; i < E; i += gridDim.x * blockDim.x) {
        int d = edge_dst(ei, E, i, is64);
        int s = edge_src(ei, E, i, is64);
        int pos = atomicAdd(&cursor[d], 1);
        src_sorted[pos] = s;
    }
}

// ---------------- GEMMs ----------------

// x[N,128] = nf[N,64] @ W_in[64,128] + b_in.  Block 256: col=t&127, rh=t>>7, 64 rows/block.
__global__ __launch_bounds__(256) void gemm_in_kernel(
        const float* __restrict__ nf, const float* __restrict__ Wi,
        const float* __restrict__ bi, float* __restrict__ x, int N) {
    __shared__ float Wl[F_IN * HID];   // 32 KB
    int t = threadIdx.x;
    for (int i = t; i < F_IN * HID; i += 256) Wl[i] = Wi[i];
    __syncthreads();
    int col = t & 127, rh = t >> 7;
    int r0 = blockIdx.x * 64;
    float bc = bi[col];
    for (int rr = 0; rr < 16; rr++) {
        int rbase = r0 + rr * 4 + rh * 2;
        bool ok0 = rbase < N, ok1 = rbase + 1 < N;
        if (!ok0) continue;
        const float* x0 = nf + (size_t)rbase * F_IN;
        const float* x1 = x0 + F_IN;
        float a0 = 0.f, a1 = 0.f;
        if (ok1) {
            #pragma unroll
            for (int k = 0; k < F_IN; k++) {
                float w = Wl[k * HID + col];
                a0 += x0[k] * w;
                a1 += x1[k] * w;
            }
        } else {
            #pragma unroll
            for (int k = 0; k < F_IN; k++) a0 += x0[k] * Wl[k * HID + col];
        }
        x[(size_t)rbase * HID + col] = a0 + bc;
        if (ok1) x[(size_t)(rbase + 1) * HID + col] = a1 + bc;
    }
}

// h[N,128] = x[N,128] @ W[128,128]; also alpha_s[n,head]=sum_d h*a_src, alpha_d likewise.
__global__ __launch_bounds__(256) void gemm_h_kernel(
        const float* __restrict__ x, const float* __restrict__ W,
        const float* __restrict__ asv, const float* __restrict__ adv,
        float* __restrict__ h, float* __restrict__ alpha_s, float* __restrict__ alpha_d,
        int N) {
    __shared__ float Wl[64 * HID];     // 32 KB, K staged in 2 chunks
    int t = threadIdx.x;
    int col = t & 127, rh = t >> 7;
    int r0 = blockIdx.x * 64;
    float acc[32];
    #pragma unroll
    for (int i = 0; i < 32; i++) acc[i] = 0.f;
    for (int kc = 0; kc < 2; kc++) {
        __syncthreads();
        for (int i = t; i < 64 * HID; i += 256) Wl[i] = W[kc * 64 * HID + i];
        __syncthreads();
        for (int rr = 0; rr < 16; rr++) {
            int rbase = r0 + rr * 4 + rh * 2;
            bool ok0 = rbase < N, ok1 = rbase + 1 < N;
            if (!ok0) continue;
            const float* x0 = x + (size_t)rbase * HID + kc * 64;
            const float* x1 = x0 + HID;
            float a0 = acc[rr * 2], a1 = acc[rr * 2 + 1];
            if (ok1) {
                #pragma unroll
                for (int k = 0; k < 64; k++) {
                    float w = Wl[k * HID + col];
                    a0 += x0[k] * w;
                    a1 += x1[k] * w;
                }
            } else {
                #pragma unroll
                for (int k = 0; k < 64; k++) a0 += x0[k] * Wl[k * HID + col];
            }
            acc[rr * 2] = a0; acc[rr * 2 + 1] = a1;
        }
    }
    float asc = asv[col], adc = adv[col];
    int head = col >> 4;
    for (int rr = 0; rr < 16; rr++) {
        #pragma unroll
        for (int j = 0; j < 2; j++) {
            int r = r0 + rr * 4 + rh * 2 + j;
            if (r >= N) continue;
            float v = acc[rr * 2 + j];
            h[(size_t)r * HID + col] = v;
            float ps = v * asc, pd = v * adc;
            #pragma unroll
            for (int msk = 1; msk < 16; msk <<= 1) {
                ps += __shfl_xor(ps, msk);
                pd += __shfl_xor(pd, msk);
            }
            if ((t & 15) == 0) {
                alpha_s[(size_t)r * HEADS + head] = ps;
                alpha_d[(size_t)r * HEADS + head] = pd;
            }
        }
    }
}

// ---------------- per-dst softmax + aggregation + epilogue ----------------
// One 64-lane wave per destination node.

__global__ __launch_bounds__(64) void agg_kernel(
        const int* __restrict__ row_ptr, const int* __restrict__ src_sorted,
        const float* __restrict__ h, const float* __restrict__ alpha_s,
        const float* __restrict__ alpha_d,
        const float* __restrict__ x_res, float* __restrict__ x_out,
        const float* __restrict__ bg, const float* __restrict__ g,
        const float* __restrict__ bb, int N) {
    int n = blockIdx.x;
    if (n >= N) return;
    int lane = threadIdx.x;
    int beg = row_ptr[n];
    int deg = row_ptr[n + 1] - beg;

    int hd = lane & 7, esub = lane >> 3;
    float ad_n = alpha_d[(size_t)n * HEADS + hd];

    // phase 1: per-head max of LeakyReLU(e)
    float m = -1e30f;
    for (int i = esub; i < deg; i += 8) {
        int s = src_sorted[beg + i];
        float ev = alpha_s[(size_t)s * HEADS + hd] + ad_n;
        ev = ev > 0.f ? ev : 0.2f * ev;
        m = fmaxf(m, ev);
    }
    m = fmaxf(m, __shfl_xor(m, 8));
    m = fmaxf(m, __shfl_xor(m, 16));
    m = fmaxf(m, __shfl_xor(m, 32));

    __shared__ float ex_lds[CHUNK * HEADS];   // 4 KB
    int hA = lane >> 4, hB = hA + 4;
    float acc0 = 0.f, acc1 = 0.f, den = 0.f;

    for (int cs = 0; cs < deg; cs += CHUNK) {
        int cn = min(deg - cs, CHUNK);
        for (int i = esub; i < cn; i += 8) {
            int s = src_sorted[beg + cs + i];
            float ev = alpha_s[(size_t)s * HEADS + hd] + ad_n;
            ev = ev > 0.f ? ev : 0.2f * ev;
            float ex = expf(ev - m);
            ex_lds[i * HEADS + hd] = ex;
            den += ex;
        }
        __syncthreads();
        #pragma unroll 4
        for (int i = 0; i < cn; i++) {
            int s = src_sorted[beg + cs + i];
            float w0 = ex_lds[i * HEADS + hA];
            float w1 = ex_lds[i * HEADS + hB];
            const float* hr = h + (size_t)s * HID;
            acc0 += w0 * hr[lane];
            acc1 += w1 * hr[64 + lane];
        }
        __syncthreads();
    }

    den += __shfl_xor(den, 8);
    den += __shfl_xor(den, 16);
    den += __shfl_xor(den, 32);
    float dA = __shfl(den, hA);   // lane k (k<8) holds denom of head k
    float dB = __shfl(den, hB);

    float v0 = 0.f, v1 = 0.f;
    if (deg > 0) { v0 = acc0 / dA; v1 = acc1 / dB; }

    v0 += bg[lane];      v1 += bg[64 + lane];
    v0 = v0 > 0.f ? v0 : expf(v0) - 1.f;     // ELU
    v1 = v1 > 0.f ? v1 : expf(v1) - 1.f;
    v0 += x_res[(size_t)n * HID + lane];
    v1 += x_res[(size_t)n * HID + 64 + lane];

    float sum = v0 + v1;
    #pragma unroll
    for (int off = 1; off < 64; off <<= 1) sum += __shfl_xor(sum, off);
    float mu = sum * (1.f / 128.f);
    float d0 = v0 - mu, d1 = v1 - mu;
    float vs = d0 * d0 + d1 * d1;
    #pragma unroll
    for (int off = 1; off < 64; off <<= 1) vs += __shfl_xor(vs, off);
    float rstd = rsqrtf(vs * (1.f / 128.f) + 1e-5f);

    x_out[(size_t)n * HID + lane]      = d0 * rstd * g[lane]      + bb[lane];
    x_out[(size_t)n * HID + 64 + lane] = d1 * rstd * g[64 + lane] + bb[64 + lane];
}

// ---------------- host launch ----------------

extern "C" void kernel_launch(void* const* d_in, const int* in_sizes, int n_in,
                              void* d_out, int out_size, void* d_ws, size_t ws_size,
                              hipStream_t stream) {
    const float* nf    = (const float*)d_in[0];
    const int*   ei    = (const int*)d_in[1];
    const float* W_in  = (const float*)d_in[2];
    const float* b_in  = (const float*)d_in[3];
    const float* W     = (const float*)d_in[4];
    const float* a_src = (const float*)d_in[5];
    const float* a_dst = (const float*)d_in[6];
    const float* b_gat = (const float*)d_in[7];
    const float* ln_g  = (const float*)d_in[8];
    const float* ln_b  = (const float*)d_in[9];
    float* out = (float*)d_out;

    const int N = in_sizes[0] / F_IN;     // 50000
    const int E = in_sizes[1] / 2;        // 1,600,000

    // workspace layout (256B aligned)
    size_t off = 0;
    auto alloc = [&](size_t bytes) -> void* {
        void* p = (char*)d_ws + off;
        off += (bytes + 255) & ~(size_t)255;
        return p;
    };
    int*   row_ptr    = (int*)alloc(sizeof(int) * (N + 1));
    int*   cursor     = (int*)alloc(sizeof(int) * N);
    int*   src_sorted = (int*)alloc(sizeof(int) * E);
    int*   flag       = (int*)alloc(sizeof(int));
    float* x          = (float*)alloc(sizeof(float) * (size_t)N * HID);
    float* h          = (float*)alloc(sizeof(float) * (size_t)N * HID);
    float* al_s       = (float*)alloc(sizeof(float) * (size_t)N * HEADS);
    float* al_d       = (float*)alloc(sizeof(float) * (size_t)N * HEADS);
    (void)ws_size;

    // CSR build
    zero_i32_kernel<<<(N + 255) / 256, 256, 0, stream>>>(cursor, N);
    detect64_kernel<<<1, 64, 0, stream>>>(ei, flag);
    hist_kernel<<<2048, 256, 0, stream>>>(ei, E, flag, cursor);
    scan_kernel<<<1, 1024, 0, stream>>>(cursor, row_ptr, N);
    scatter_kernel<<<2048, 256, 0, stream>>>(ei, E, flag, cursor, src_sorted);

    // input projection
    int gemm_grid = (N + 63) / 64;
    gemm_in_kernel<<<gemm_grid, 256, 0, stream>>>(nf, W_in, b_in, x, N);

    // layers
    for (int layer = 0; layer < 2; layer++) {
        gemm_h_kernel<<<gemm_grid, 256, 0, stream>>>(
            x, W + (size_t)layer * HID * HID,
            a_src + (size_t)layer * HID, a_dst + (size_t)layer * HID,
            h, al_s, al_d, N);
        float* xo = (layer == 1) ? out : x;   // layer0 in-place, layer1 -> d_out
        agg_kernel<<<N, 64, 0, stream>>>(
            row_ptr, src_sorted, h, al_s, al_d,
            x, xo,
            b_gat + (size_t)layer * HID, ln_g + (size_t)layer * HID,
            ln_b + (size_t)layer * HID, N);
    }
}

// Round 2
// 499.285 us; speedup vs baseline: 1.8837x; 1.8837x over previous
//
#include <hip/hip_runtime.h>
#include <hip/hip_bf16.h>
#include <math.h>

// GAT forward: N=50000, E=1.6M, F_IN=64, HID=128, HEADS=8, D_HEAD=16, 2 layers.
// R2: LDS-tiled fp32 GEMMs (A+B staged, float4), bf16 h for the edge gather,
// 4-wave agg blocks with LDS-cached edge weights, hierarchical CSR scan.

#define F_IN 64
#define HID 128
#define HEADS 8
#define CHUNK 128

typedef unsigned short ushort_t;

static __device__ __forceinline__ ushort_t f2bf(float f) {
    unsigned int u = __float_as_uint(f);
    unsigned int r = (u + 0x7fffu + ((u >> 16) & 1u)) >> 16;
    return (ushort_t)r;
}
static __device__ __forceinline__ float bf2f(ushort_t b) {
    return __uint_as_float(((unsigned int)b) << 16);
}

// ---------------- CSR build ----------------

__global__ void zero_i32_kernel(int* __restrict__ p, int n) {
    int i = blockIdx.x * blockDim.x + threadIdx.x;
    if (i < n) p[i] = 0;
}

__global__ void detect64_kernel(const int* __restrict__ ei, int* __restrict__ flag) {
    if (threadIdx.x == 0 && blockIdx.x == 0) {
        int any_odd = 0;
        for (int i = 0; i < 256; i++) any_odd |= ei[2 * i + 1];
        *flag = (any_odd == 0) ? 1 : 0;   // 1 => int64 layout
    }
}

__global__ void hist_kernel(const int* __restrict__ ei, int E,
                            const int* __restrict__ flag, int* __restrict__ counts) {
    int is64 = *flag;
    int stride = gridDim.x * blockDim.x;
    int i0 = blockIdx.x * blockDim.x + threadIdx.x;
    if (is64) {
        for (int i = i0; i < E; i += stride) atomicAdd(&counts[ei[2 * (E + i)]], 1);
    } else {
        for (int i = i0; i < E; i += stride) atomicAdd(&counts[ei[E + i]], 1);
    }
}

// block partial sums
__global__ __launch_bounds__(256) void scan_partial_kernel(
        const int* __restrict__ counts, int n, int* __restrict__ bsum) {
    int i = blockIdx.x * 256 + threadIdx.x;
    int v = (i < n) ? counts[i] : 0;
    #pragma unroll
    for (int off = 1; off < 64; off <<= 1) v += __shfl_xor(v, off);
    __shared__ int ws[4];
    if ((threadIdx.x & 63) == 0) ws[threadIdx.x >> 6] = v;
    __syncthreads();
    if (threadIdx.x == 0) bsum[blockIdx.x] = ws[0] + ws[1] + ws[2] + ws[3];
}

// exclusive scan of <=256 block sums, single block
__global__ __launch_bounds__(256) void scan_tops_kernel(
        const int* __restrict__ bsum, int nb, int* __restrict__ bpre) {
    int t = threadIdx.x;
    int v = (t < nb) ? bsum[t] : 0;
    int lane = t & 63, w = t >> 6;
    int inc = v;
    #pragma unroll
    for (int off = 1; off < 64; off <<= 1) {
        int o = __shfl_up(inc, off);
        if (lane >= off) inc += o;
    }
    __shared__ int wz[4];
    if (lane == 63) wz[w] = inc;
    __syncthreads();
    int add = 0;
    for (int k = 0; k < w; k++) add += wz[k];
    if (t < nb) bpre[t] = add + inc - v;
}

__global__ __launch_bounds__(256) void scan_final_kernel(
        const int* __restrict__ counts, int n, const int* __restrict__ bpre,
        int* __restrict__ row_ptr, int* __restrict__ cursor) {
    int b = blockIdx.x, t = threadIdx.x;
    int i = b * 256 + t;
    int v = (i < n) ? counts[i] : 0;
    int lane = t & 63, w = t >> 6;
    int inc = v;
    #pragma unroll
    for (int off = 1; off < 64; off <<= 1) {
        int o = __shfl_up(inc, off);
        if (lane >= off) inc += o;
    }
    __shared__ int wz[4];
    if (lane == 63) wz[w] = inc;
    __syncthreads();
    int add = bpre[b];
    for (int k = 0; k < w; k++) add += wz[k];
    int excl = add + inc - v;
    if (i < n) {
        row_ptr[i] = excl;
        cursor[i] = excl;
        if (i == n - 1) row_ptr[n] = excl + v;
    }
}

__global__ void scatter_kernel(const int* __restrict__ ei, int E,
                               const int* __restrict__ flag,
                               int* __restrict__ cursor, int* __restrict__ src_sorted) {
    int is64 = *flag;
    int stride = gridDim.x * blockDim.x;
    int i0 = blockIdx.x * blockDim.x + threadIdx.x;
    if (is64) {
        for (int i = i0; i < E; i += stride) {
            int d = ei[2 * (E + i)];
            int s = ei[2 * i];
            src_sorted[atomicAdd(&cursor[d], 1)] = s;
        }
    } else {
        for (int i = i0; i < E; i += stride) {
            int d = ei[E + i];
            int s = ei[i];
            src_sorted[atomicAdd(&cursor[d], 1)] = s;
        }
    }
}

// ---------------- GEMM ----------------
// C[M,128] = A[M,K] @ B[K,128]. 64 rows/block, 256 threads.
// thread: cols c4..c4+3 (c4=(t&31)*4), rows rg*8..rg*8+7 (rg=t>>5).
// IN_PROJ: +bias, fp32 out to xout.  else: bf16 out to hbf + fused alpha_s/alpha_d.
template<int K, bool IN_PROJ>
__global__ __launch_bounds__(256) void gemm_kernel(
        const float* __restrict__ A, const float* __restrict__ B,
        const float* __restrict__ bias,
        const float* __restrict__ asv, const float* __restrict__ adv,
        float* __restrict__ xout, ushort_t* __restrict__ hbf,
        float* __restrict__ alpha_s, float* __restrict__ alpha_d, int M) {
    __shared__ float Al[64 * 32];
    __shared__ float Bl[32 * 128];
    int t = threadIdx.x;
    int r0 = blockIdx.x * 64;
    int c4 = (t & 31) * 4;
    int rg = t >> 5;
    float4 acc[8];
    #pragma unroll
    for (int j = 0; j < 8; j++) acc[j] = make_float4(0.f, 0.f, 0.f, 0.f);

    for (int kc = 0; kc < K / 32; kc++) {
        __syncthreads();
        {   // stage A: 64 x 32
            int row = t >> 3, q = (t & 7) * 4;
            #pragma unroll
            for (int half = 0; half < 2; half++) {
                int rr = row + half * 32;
                int gr = r0 + rr;
                float4 v = make_float4(0.f, 0.f, 0.f, 0.f);
                if (gr < M) v = *(const float4*)(A + (size_t)gr * K + kc * 32 + q);
                *(float4*)&Al[rr * 32 + q] = v;
            }
        }
        {   // stage B: 32 x 128
            #pragma unroll
            for (int p = 0; p < 4; p++) {
                int idx = p * 256 + t;
                int br = idx >> 5, bq = (idx & 31) * 4;
                *(float4*)&Bl[br * 128 + bq] =
                    *(const float4*)(B + (size_t)(kc * 32 + br) * 128 + bq);
            }
        }
        __syncthreads();
        #pragma unroll
        for (int k = 0; k < 32; k += 4) {
            float4 b0 = *(float4*)&Bl[(k + 0) * 128 + c4];
            float4 b1 = *(float4*)&Bl[(k + 1) * 128 + c4];
            float4 b2 = *(float4*)&Bl[(k + 2) * 128 + c4];
            float4 b3 = *(float4*)&Bl[(k + 3) * 128 + c4];
            #pragma unroll
            for (int j = 0; j < 8; j++) {
                float4 a = *(float4*)&Al[(rg * 8 + j) * 32 + k];
                acc[j].x += a.x * b0.x; acc[j].y += a.x * b0.y;
                acc[j].z += a.x * b0.z; acc[j].w += a.x * b0.w;
                acc[j].x += a.y * b1.x; acc[j].y += a.y * b1.y;
                acc[j].z += a.y * b1.z; acc[j].w += a.y * b1.w;
                acc[j].x += a.z * b2.x; acc[j].y += a.z * b2.y;
                acc[j].z += a.z * b2.z; acc[j].w += a.z * b2.w;
                acc[j].x += a.w * b3.x; acc[j].y += a.w * b3.y;
                acc[j].z += a.w * b3.z; acc[j].w += a.w * b3.w;
            }
        }
    }

    if (IN_PROJ) {
        float4 bv = *(const float4*)(bias + c4);
        #pragma unroll
        for (int j = 0; j < 8; j++) {
            int r = r0 + rg * 8 + j;
            if (r >= M) continue;
            float4 o = acc[j];
            o.x += bv.x; o.y += bv.y; o.z += bv.z; o.w += bv.w;
            *(float4*)(xout + (size_t)r * 128 + c4) = o;
        }
    } else {
        float4 asf = *(const float4*)(asv + c4);
        float4 adf = *(const float4*)(adv + c4);
        int head = (t & 31) >> 2;
        #pragma unroll
        for (int j = 0; j < 8; j++) {
            int r = r0 + rg * 8 + j;
            if (r >= M) continue;   // whole quad uniform (same rg)
            float4 o = acc[j];
            ushort4 hb;
            hb.x = f2bf(o.x); hb.y = f2bf(o.y); hb.z = f2bf(o.z); hb.w = f2bf(o.w);
            *(ushort4*)(hbf + (size_t)r * 128 + c4) = hb;
            float ps = o.x * asf.x + o.y * asf.y + o.z * asf.z + o.w * asf.w;
            float pd = o.x * adf.x + o.y * adf.y + o.z * adf.z + o.w * adf.w;
            ps += __shfl_xor(ps, 1); ps += __shfl_xor(ps, 2);
            pd += __shfl_xor(pd, 1); pd += __shfl_xor(pd, 2);
            if ((t & 3) == 0) {
                alpha_s[(size_t)r * HEADS + head] = ps;
                alpha_d[(size_t)r * HEADS + head] = pd;
            }
        }
    }
}

// ---------------- softmax + aggregation + epilogue ----------------
// 4 waves/block, one node per wave, no __syncthreads (wave-synchronous LDS).
// lane roles: phase1/2: hd=lane&7 (head), esub=lane>>3 (edge slot).
//             aggregation: lane owns dims {2*lane, 2*lane+1}, head g=lane>>3.

__global__ __launch_bounds__(256) void agg_kernel(
        const int* __restrict__ row_ptr, const int* __restrict__ src_sorted,
        const ushort_t* __restrict__ hbf, const float* __restrict__ alpha_s,
        const float* __restrict__ alpha_d,
        const float* __restrict__ x_res, float* __restrict__ x_out,
        const float* __restrict__ bg, const float* __restrict__ g,
        const float* __restrict__ bb, int N) {
    __shared__ float ex_s[4][CHUNK * HEADS];   // 16 KB
    __shared__ int   src_s[4][CHUNK];          // 2 KB
    int wid = threadIdx.x >> 6, lane = threadIdx.x & 63;
    int n = blockIdx.x * 4 + wid;
    if (n >= N) return;
    float* exl = ex_s[wid];
    int*   srl = src_s[wid];

    int beg = row_ptr[n];
    int deg = row_ptr[n + 1] - beg;
    int hd = lane & 7, esub = lane >> 3;
    float ad_n = alpha_d[(size_t)n * HEADS + hd];

    float m = -1e30f;
    float den = 0.f;
    float accx = 0.f, accy = 0.f;
    int gh = lane >> 3;              // head for aggregation dims

    if (deg <= CHUNK) {
        // ---- cached single-chunk path ----
        for (int i = esub; i < deg; i += 8) {
            int s = src_sorted[beg + i];
            if (hd == 0) srl[i] = s;
            float ev = alpha_s[(size_t)s * HEADS + hd] + ad_n;
            ev = ev > 0.f ? ev : 0.2f * ev;
            exl[i * HEADS + hd] = ev;
            m = fmaxf(m, ev);
        }
        m = fmaxf(m, __shfl_xor(m, 8));
        m = fmaxf(m, __shfl_xor(m, 16));
        m = fmaxf(m, __shfl_xor(m, 32));
        for (int i = esub; i < deg; i += 8) {
            float ex = __expf(exl[i * HEADS + hd] - m);
            exl[i * HEADS + hd] = ex;
            den += ex;
        }
        __builtin_amdgcn_wave_barrier();
        // aggregation, unroll 2 with independent chains
        float a0x = 0.f, a0y = 0.f, a1x = 0.f, a1y = 0.f;
        int i = 0;
        for (; i + 2 <= deg; i += 2) {
            int s0 = srl[i], s1 = srl[i + 1];
            float w0 = exl[i * HEADS + gh];
            float w1 = exl[(i + 1) * HEADS + gh];
            ushort2 h0 = *(const ushort2*)(hbf + (size_t)s0 * 128 + 2 * lane);
            ushort2 h1 = *(const ushort2*)(hbf + (size_t)s1 * 128 + 2 * lane);
            a0x += w0 * bf2f(h0.x); a0y += w0 * bf2f(h0.y);
            a1x += w1 * bf2f(h1.x); a1y += w1 * bf2f(h1.y);
        }
        if (i < deg) {
            int s0 = srl[i];
            float w0 = exl[i * HEADS + gh];
            ushort2 h0 = *(const ushort2*)(hbf + (size_t)s0 * 128 + 2 * lane);
            a0x += w0 * bf2f(h0.x); a0y += w0 * bf2f(h0.y);
        }
        accx = a0x + a1x; accy = a0y + a1y;
    } else {
        // ---- generic chunked path ----
        for (int i = esub; i < deg; i += 8) {
            int s = src_sorted[beg + i];
            float ev = alpha_s[(size_t)s * HEADS + hd] + ad_n;
            ev = ev > 0.f ? ev : 0.2f * ev;
            m = fmaxf(m, ev);
        }
        m = fmaxf(m, __shfl_xor(m, 8));
        m = fmaxf(m, __shfl_xor(m, 16));
        m = fmaxf(m, __shfl_xor(m, 32));
        for (int cs = 0; cs < deg; cs += CHUNK) {
            int cn = min(deg - cs, CHUNK);
            for (int i = esub; i < cn; i += 8) {
                int s = src_sorted[beg + cs + i];
                if (hd == 0) srl[i] = s;
                float ev = alpha_s[(size_t)s * HEADS + hd] + ad_n;
                ev = ev > 0.f ? ev : 0.2f * ev;
                float ex = __expf(ev - m);
                exl[i * HEADS + hd] = ex;
                den += ex;
            }
            __builtin_amdgcn_wave_barrier();
            for (int i = 0; i < cn; i++) {
                int s0 = srl[i];
                float w0 = exl[i * HEADS + gh];
                ushort2 h0 = *(const ushort2*)(hbf + (size_t)s0 * 128 + 2 * lane);
                accx += w0 * bf2f(h0.x); accy += w0 * bf2f(h0.y);
            }
            __builtin_amdgcn_wave_barrier();
        }
    }

    den += __shfl_xor(den, 8);
    den += __shfl_xor(den, 16);
    den += __shfl_xor(den, 32);
    float dn = __shfl(den, gh);   // lane k (k<8) holds denom of head k

    float v0 = 0.f, v1 = 0.f;
    if (deg > 0) { v0 = accx / dn; v1 = accy / dn; }

    float2 bgv = *(const float2*)(bg + 2 * lane);
    v0 += bgv.x; v1 += bgv.y;
    v0 = v0 > 0.f ? v0 : __expf(v0) - 1.f;   // ELU
    v1 = v1 > 0.f ? v1 : __expf(v1) - 1.f;
    float2 rv = *(const float2*)(x_res + (size_t)n * 128 + 2 * lane);
    v0 += rv.x; v1 += rv.y;

    float sum = v0 + v1;
    #pragma unroll
    for (int off = 1; off < 64; off <<= 1) sum += __shfl_xor(sum, off);
    float mu = sum * (1.f / 128.f);
    float d0 = v0 - mu, d1 = v1 - mu;
    float vs = d0 * d0 + d1 * d1;
    #pragma unroll
    for (int off = 1; off < 64; off <<= 1) vs += __shfl_xor(vs, off);
    float rstd = rsqrtf(vs * (1.f / 128.f) + 1e-5f);

    float2 gv = *(const float2*)(g + 2 * lane);
    float2 bv = *(const float2*)(bb + 2 * lane);
    float2 ov;
    ov.x = d0 * rstd * gv.x + bv.x;
    ov.y = d1 * rstd * gv.y + bv.y;
    *(float2*)(x_out + (size_t)n * 128 + 2 * lane) = ov;
}

// ---------------- host launch ----------------

extern "C" void kernel_launch(void* const* d_in, const int* in_sizes, int n_in,
                              void* d_out, int out_size, void* d_ws, size_t ws_size,
                              hipStream_t stream) {
    const float* nf    = (const float*)d_in[0];
    const int*   ei    = (const int*)d_in[1];
    const float* W_in  = (const float*)d_in[2];
    const float* b_in  = (const float*)d_in[3];
    const float* W     = (const float*)d_in[4];
    const float* a_src = (const float*)d_in[5];
    const float* a_dst = (const float*)d_in[6];
    const float* b_gat = (const float*)d_in[7];
    const float* ln_g  = (const float*)d_in[8];
    const float* ln_b  = (const float*)d_in[9];
    float* out = (float*)d_out;

    const int N = in_sizes[0] / F_IN;     // 50000
    const int E = in_sizes[1] / 2;        // 1,600,000
    const int NB = (N + 255) / 256;       // scan blocks (<=256)

    size_t off = 0;
    auto alloc = [&](size_t bytes) -> void* {
        void* p = (char*)d_ws + off;
        off += (bytes + 255) & ~(size_t)255;
        return p;
    };
    int*      row_ptr    = (int*)alloc(sizeof(int) * (N + 1));
    int*      counts     = (int*)alloc(sizeof(int) * N);
    int*      cursor     = (int*)alloc(sizeof(int) * N);
    int*      src_sorted = (int*)alloc(sizeof(int) * E);
    int*      flag       = (int*)alloc(sizeof(int));
    int*      bsum       = (int*)alloc(sizeof(int) * 256);
    int*      bpre       = (int*)alloc(sizeof(int) * 256);
    float*    x          = (float*)alloc(sizeof(float) * (size_t)N * HID);
    ushort_t* hbf        = (ushort_t*)alloc(sizeof(ushort_t) * (size_t)N * HID);
    float*    al_s       = (float*)alloc(sizeof(float) * (size_t)N * HEADS);
    float*    al_d       = (float*)alloc(sizeof(float) * (size_t)N * HEADS);
    (void)ws_size;

    // CSR build
    zero_i32_kernel<<<(N + 255) / 256, 256, 0, stream>>>(counts, N);
    detect64_kernel<<<1, 64, 0, stream>>>(ei, flag);
    hist_kernel<<<2048, 256, 0, stream>>>(ei, E, flag, counts);
    scan_partial_kernel<<<NB, 256, 0, stream>>>(counts, N, bsum);
    scan_tops_kernel<<<1, 256, 0, stream>>>(bsum, NB, bpre);
    scan_final_kernel<<<NB, 256, 0, stream>>>(counts, N, bpre, row_ptr, cursor);
    scatter_kernel<<<2048, 256, 0, stream>>>(ei, E, flag, cursor, src_sorted);

    int gemm_grid = (N + 63) / 64;
    gemm_kernel<F_IN, true><<<gemm_grid, 256, 0, stream>>>(
        nf, W_in, b_in, nullptr, nullptr, x, nullptr, nullptr, nullptr, N);

    for (int layer = 0; layer < 2; layer++) {
        gemm_kernel<HID, false><<<gemm_grid, 256, 0, stream>>>(
            x, W + (size_t)layer * HID * HID, nullptr,
            a_src + (size_t)layer * HID, a_dst + (size_t)layer * HID,
            nullptr, hbf, al_s, al_d, N);
        float* xo = (layer == 1) ? out : x;
        agg_kernel<<<(N + 3) / 4, 256, 0, stream>>>(
            row_ptr, src_sorted, hbf, al_s, al_d,
            x, xo,
            b_gat + (size_t)layer * HID, ln_g + (size_t)layer * HID,
            ln_b + (size_t)layer * HID, N);
    }
}